// Round 1
// baseline (197.449 us; speedup 1.0000x reference)
//
#include <hip/hip_runtime.h>

#define BB 64
#define C1 3
#define LIN 8192
#define PAD1 2
#define LPAD 8196      // 8192 + 2*2
#define O1 6
#define KK1 80
#define LP1 4058       // floor((8196-80+1)/2)

#define O2 16
#define KK2 3
#define LP2 2028       // floor((4058-3+1)/2)

#define NFLAT 32448    // 16*2028
#define H1 120
#define H2 84
#define NOUT 10

#define FLTMAX 3.402823466e+38f

// ---------------- Kernel 1: tropical min-plus conv1 (K=80, pad=2) + avgpool2 ----------------
// grid = 64 b * 32 tiles of 128 pooled outputs; block 256
#define T1 128
#define XT1 340        // need 2*T1+79 = 335 x values per channel, padded

__global__ __launch_bounds__(256) void k_conv1(const float* __restrict__ x,
                                               const float* __restrict__ w1,
                                               float* __restrict__ p1) {
  __shared__ float xs[C1][XT1];
  __shared__ float wl[C1 * KK1 * 8];   // wl[(c*80+k)*8 + o]
  const int b    = blockIdx.x >> 5;
  const int tile = blockIdx.x & 31;
  const int j0   = tile * T1;
  const int t0   = 2 * j0;             // base padded-index of this tile
  const int tid  = threadIdx.x;

  // stage weights, transposed for per-o broadcast reads
  for (int idx = tid; idx < O1 * C1 * KK1; idx += 256) {
    int o = idx / (C1 * KK1);
    int r = idx - o * (C1 * KK1);
    int c = r / KK1;
    int k = r - c * KK1;
    wl[(c * KK1 + k) * 8 + o] = w1[idx];
  }
  // stage x with zero padding
  for (int idx = tid; idx < C1 * XT1; idx += 256) {
    int c = idx / XT1;
    int p = idx - c * XT1;
    int g = t0 + p;          // padded coordinate
    int gi = g - PAD1;
    float v = 0.f;
    if (gi >= 0 && gi < LIN && g < LPAD) v = x[(b * C1 + c) * LIN + gi];
    xs[c][p] = v;
  }
  __syncthreads();

  const int og = tid >> 7;          // wave-uniform: 0 or 1
  const int ob = og * 3;            // o in {ob, ob+1, ob+2}
  const int jj = tid & 127;
  const int j  = j0 + jj;
  if (j >= LP1) return;
  const int lb = 2 * jj;

  float sA0 = 0.f, sA1 = 0.f, sA2 = 0.f;   // conv output at t=2j, per o
  float sB0 = 0.f, sB1 = 0.f, sB2 = 0.f;   // conv output at t=2j+1, per o

  for (int c = 0; c < C1; ++c) {
    const float* xp = &xs[c][lb];
    const float* wp = &wl[c * KK1 * 8 + ob];
    float m00 = FLTMAX, m01 = FLTMAX;
    float m10 = FLTMAX, m11 = FLTMAX;
    float m20 = FLTMAX, m21 = FLTMAX;
#pragma unroll 8
    for (int kp = 0; kp < KK1; kp += 2) {
      float xa = xp[kp];
      float xb = xp[kp + 1];
      float xc = xp[kp + 2];
      float w00 = wp[kp * 8 + 0], w01 = wp[kp * 8 + 8];
      float w10 = wp[kp * 8 + 1], w11 = wp[kp * 8 + 9];
      float w20 = wp[kp * 8 + 2], w21 = wp[kp * 8 + 10];
      // min3 folding: fmin(fmin(acc,a),b) -> v_min3_f32
      m00 = fminf(fminf(m00, xa + w00), xb + w01);
      m01 = fminf(fminf(m01, xb + w00), xc + w01);
      m10 = fminf(fminf(m10, xa + w10), xb + w11);
      m11 = fminf(fminf(m11, xb + w10), xc + w11);
      m20 = fminf(fminf(m20, xa + w20), xb + w21);
      m21 = fminf(fminf(m21, xb + w20), xc + w21);
    }
    sA0 += m00; sB0 += m01;
    sA1 += m10; sB1 += m11;
    sA2 += m20; sB2 += m21;
  }
  p1[((size_t)b * O1 + ob + 0) * LP1 + j] = 0.5f * (sA0 + sB0);
  p1[((size_t)b * O1 + ob + 1) * LP1 + j] = 0.5f * (sA1 + sB1);
  p1[((size_t)b * O1 + ob + 2) * LP1 + j] = 0.5f * (sA2 + sB2);
}

// ---------------- Kernel 2: tropical max-plus conv2 (K=3) + avgpool2, flattened output ----------------
// grid = 64 b * 8 tiles of 256 pooled outputs; block 256
#define T2 256
#define XT2 516        // 2*T2+4 window per channel

__global__ __launch_bounds__(256) void k_conv2(const float* __restrict__ p1,
                                               const float* __restrict__ w2,
                                               float* __restrict__ p2) {
  __shared__ float ps[O1][XT2];
  __shared__ float ws[O2 * O1 * KK2];
  const int b    = blockIdx.x >> 3;
  const int tile = blockIdx.x & 7;
  const int j0   = tile * T2;
  const int tid  = threadIdx.x;

  for (int idx = tid; idx < O2 * O1 * KK2; idx += 256) ws[idx] = w2[idx];
  for (int idx = tid; idx < O1 * XT2; idx += 256) {
    int c = idx / XT2;
    int p = idx - c * XT2;
    int t = 2 * j0 + p;
    ps[c][p] = (t < LP1) ? p1[((size_t)b * O1 + c) * LP1 + t] : 0.f;
  }
  __syncthreads();

  const int j = j0 + tid;
  if (j >= LP2) return;
  const int lb = 2 * tid;
  float xv[O1][4];
#pragma unroll
  for (int c = 0; c < O1; ++c) {
    xv[c][0] = ps[c][lb];     xv[c][1] = ps[c][lb + 1];
    xv[c][2] = ps[c][lb + 2]; xv[c][3] = ps[c][lb + 3];
  }
#pragma unroll
  for (int o = 0; o < O2; ++o) {
    float s = 0.f;
#pragma unroll
    for (int c = 0; c < O1; ++c) {
      float w0 = ws[(o * O1 + c) * KK2 + 0];
      float w1v = ws[(o * O1 + c) * KK2 + 1];
      float w2v = ws[(o * O1 + c) * KK2 + 2];
      float m0 = fmaxf(fmaxf(xv[c][0] + w0, xv[c][1] + w1v), xv[c][2] + w2v);
      float m1 = fmaxf(fmaxf(xv[c][1] + w0, xv[c][2] + w1v), xv[c][3] + w2v);
      s += m0 + m1;
    }
    p2[(size_t)b * NFLAT + o * LP2 + j] = 0.5f * s;
  }
}

// ---------------- Kernel 3: FC1 split-K partials ----------------
// grid = 254 K-chunks of 128; block 256 = 16 bq * 16 it; per-thread 4b x 8i
#define KC 128
#define NKC 254        // ceil(32448/128)

__global__ __launch_bounds__(256) void k_fc1(const float* __restrict__ p2,
                                             const float* __restrict__ w,
                                             float* __restrict__ part) {
  __shared__ float xs[BB][68];       // [b][k], pad 68 -> bank shift 4/row
  __shared__ float wsh[128][68];     // [i][k], rows 120..127 zero
  const int kc  = blockIdx.x;
  const int tid = threadIdx.x;
  const int bq  = tid & 15;
  const int it  = tid >> 4;

  float acc[4][8];
#pragma unroll
  for (int u = 0; u < 4; ++u)
#pragma unroll
    for (int m = 0; m < 8; ++m) acc[u][m] = 0.f;

  for (int ks = 0; ks < KC; ks += 64) {
    const int kb = kc * KC + ks;     // multiple of 64; chunk fully valid or fully OOB
    for (int idx = tid; idx < BB * 16; idx += 256) {
      int row = idx >> 4, c4 = idx & 15;
      int k = kb + c4 * 4;
      float4 v = make_float4(0.f, 0.f, 0.f, 0.f);
      if (k < NFLAT) v = *(const float4*)&p2[(size_t)row * NFLAT + k];
      *(float4*)&xs[row][c4 * 4] = v;
    }
    for (int idx = tid; idx < 128 * 16; idx += 256) {
      int row = idx >> 4, c4 = idx & 15;
      int k = kb + c4 * 4;
      float4 v = make_float4(0.f, 0.f, 0.f, 0.f);
      if (row < H1 && k < NFLAT) v = *(const float4*)&w[(size_t)row * NFLAT + k];
      *(float4*)&wsh[row][c4 * 4] = v;
    }
    __syncthreads();
#pragma unroll 4
    for (int k = 0; k < 64; ++k) {
      float xv0 = xs[bq][k], xv1 = xs[bq + 16][k];
      float xv2 = xs[bq + 32][k], xv3 = xs[bq + 48][k];
#pragma unroll
      for (int m = 0; m < 8; ++m) {
        float wv = wsh[it + 16 * m][k];
        acc[0][m] += xv0 * wv;
        acc[1][m] += xv1 * wv;
        acc[2][m] += xv2 * wv;
        acc[3][m] += xv3 * wv;
      }
    }
    __syncthreads();
  }
  // part[kc][i*64 + b]
#pragma unroll
  for (int m = 0; m < 8; ++m) {
    int i = it + 16 * m;
    if (i < H1) {
#pragma unroll
      for (int u = 0; u < 4; ++u)
        part[(size_t)kc * (H1 * BB) + i * BB + (bq + 16 * u)] = acc[u][m];
    }
  }
}

// ---------------- Kernel 3b: reduce partials -> h1 in [i][b] layout ----------------
__global__ __launch_bounds__(256) void k_fc1red(const float* __restrict__ part,
                                                float* __restrict__ h1) {
  const int lin = blockIdx.x * 256 + threadIdx.x;   // i*64 + b
  if (lin >= H1 * BB) return;
  float s = 0.f;
  for (int kc = 0; kc < NKC; ++kc) s += part[(size_t)kc * (H1 * BB) + lin];
  h1[lin] = s;
}

// ---------------- Kernel 4: bias+ReLU, FC2+ReLU, FC3 ----------------
__global__ __launch_bounds__(128) void k_head(const float* __restrict__ h1,
                                              const float* __restrict__ fc1_b,
                                              const float* __restrict__ fc2_w,
                                              const float* __restrict__ fc2_b,
                                              const float* __restrict__ fc3_w,
                                              const float* __restrict__ fc3_b,
                                              float* __restrict__ out) {
  __shared__ float h1s[H1];
  __shared__ float h2s[H2];
  const int b = blockIdx.x;
  const int tid = threadIdx.x;
  if (tid < H1) h1s[tid] = fmaxf(h1[tid * BB + b] + fc1_b[tid], 0.f);
  __syncthreads();
  if (tid < H2) {
    float s = fc2_b[tid];
#pragma unroll 4
    for (int n = 0; n < H1; ++n) s += h1s[n] * fc2_w[tid * H1 + n];
    h2s[tid] = fmaxf(s, 0.f);
  }
  __syncthreads();
  if (tid < NOUT) {
    float s = fc3_b[tid];
#pragma unroll 4
    for (int n = 0; n < H2; ++n) s += h2s[n] * fc3_w[tid * H2 + n];
    out[b * NOUT + tid] = s;
  }
}

extern "C" void kernel_launch(void* const* d_in, const int* in_sizes, int n_in,
                              void* d_out, int out_size, void* d_ws, size_t ws_size,
                              hipStream_t stream) {
  const float* x     = (const float*)d_in[0];
  const float* w1    = (const float*)d_in[1];
  const float* w2    = (const float*)d_in[2];
  const float* fc1_w = (const float*)d_in[3];
  const float* fc1_b = (const float*)d_in[4];
  const float* fc2_w = (const float*)d_in[5];
  const float* fc2_b = (const float*)d_in[6];
  const float* fc3_w = (const float*)d_in[7];
  const float* fc3_b = (const float*)d_in[8];

  float* ws   = (float*)d_ws;
  float* p1   = ws;                                   // 64*6*4058
  float* p2   = p1 + (size_t)BB * O1 * LP1;           // 64*32448
  float* part = p2 + (size_t)BB * NFLAT;              // 254*120*64
  float* h1   = part + (size_t)NKC * H1 * BB;         // 120*64
  float* out  = (float*)d_out;

  hipLaunchKernelGGL(k_conv1, dim3(BB * 32), dim3(256), 0, stream, x, w1, p1);
  hipLaunchKernelGGL(k_conv2, dim3(BB * 8), dim3(256), 0, stream, p1, w2, p2);
  hipLaunchKernelGGL(k_fc1, dim3(NKC), dim3(256), 0, stream, p2, fc1_w, part);
  hipLaunchKernelGGL(k_fc1red, dim3((H1 * BB + 255) / 256), dim3(256), 0, stream, part, h1);
  hipLaunchKernelGGL(k_head, dim3(BB), dim3(128), 0, stream, h1, fc1_b, fc2_w, fc2_b,
                     fc3_w, fc3_b, out);
}

// Round 2
// 194.596 us; speedup vs baseline: 1.0147x; 1.0147x over previous
//
#include <hip/hip_runtime.h>

#define BB 64
#define C1 3
#define LIN 8192
#define PAD1 2
#define O1 6
#define KK1 80
#define LP1 4058       // pooled length after conv1(pad=2,K=80) + avgpool2

#define O2 16
#define KK2 3
#define LP2 2028

#define NFLAT 32448    // 16*2028
#define H1 120
#define H2 84
#define NOUT 10

#define FLTMAX 3.402823466e+38f

// ---------------- Kernel 1: tropical min-plus conv1 + avgpool2 ----------------
// Deinterleaved even/odd x in LDS (stride-1 lane reads, no 4-way conflicts),
// sliding window in regs (2 LDS reads per c,k-pair), w read wave-uniformly from
// global (expect s_load; worst case L1-hit VMEM — off the LDS pipe either way).
// grid = 64 b * 16 tiles of 256 pooled outputs; block 256, 1 pooled j + all 6 o per thread.
#define TJ1 256
#define NT1 16
#define XW 296          // window pairs per tile: 2*256+80 = 592 -> 296 per parity

__global__ __launch_bounds__(256) void k_conv1(const float* __restrict__ x,
                                               const float* __restrict__ w1,
                                               float* __restrict__ p1) {
  __shared__ float xe[C1][304];
  __shared__ float xo[C1][304];
  const int b    = blockIdx.x >> 4;
  const int tile = blockIdx.x & 15;
  const int j0   = tile * TJ1;
  const int tid  = threadIdx.x;

  // stage x, deinterleaved by parity, zero-padded
  for (int q = tid; q < C1 * XW; q += 256) {
    int c = q / XW;
    int t = q - c * XW;
    int g = 2 * (j0 + t) - PAD1;               // global idx of even element (always even)
    const float* xc = x + ((size_t)b * C1 + c) * LIN;
    float f0 = 0.f, f1 = 0.f;
    if (g >= 0 && g + 1 < LIN) {
      float2 v = *(const float2*)(xc + g);
      f0 = v.x; f1 = v.y;
    } else {
      if ((unsigned)g < LIN) f0 = xc[g];
      if ((unsigned)(g + 1) < LIN) f1 = xc[g + 1];
    }
    xe[c][t] = f0;
    xo[c][t] = f1;
  }
  __syncthreads();

  const int jj = tid;
  const int j  = j0 + jj;

  float s0 = 0.f, s1 = 0.f, s2 = 0.f, s3 = 0.f, s4 = 0.f, s5 = 0.f;

#pragma unroll
  for (int c = 0; c < C1; ++c) {
    float accA[O1], accB[O1];
#pragma unroll
    for (int o = 0; o < O1; ++o) { accA[o] = FLTMAX; accB[o] = FLTMAX; }
    float e0 = xe[c][jj];
    for (int mc = 0; mc < 10; ++mc) {        // 10 chunks of 4 k-pairs
#pragma unroll
      for (int mm = 0; mm < 4; ++mm) {
        const int m = mc * 4 + mm;
        float o0 = xo[c][jj + m];
        float e1 = xe[c][jj + m + 1];
#pragma unroll
        for (int o = 0; o < O1; ++o) {
          // wave-uniform global read (2m even -> 8B aligned float2)
          float2 w = *(const float2*)&w1[(o * C1 + c) * KK1 + 2 * m];
          accA[o] = fminf(fminf(accA[o], e0 + w.x), o0 + w.y);
          accB[o] = fminf(fminf(accB[o], o0 + w.x), e1 + w.y);
        }
        e0 = e1;
      }
    }
    s0 += accA[0] + accB[0];
    s1 += accA[1] + accB[1];
    s2 += accA[2] + accB[2];
    s3 += accA[3] + accB[3];
    s4 += accA[4] + accB[4];
    s5 += accA[5] + accB[5];
  }
  if (j < LP1) {
    float* pb = p1 + (size_t)b * O1 * LP1 + j;
    pb[0 * LP1] = 0.5f * s0;
    pb[1 * LP1] = 0.5f * s1;
    pb[2 * LP1] = 0.5f * s2;
    pb[3 * LP1] = 0.5f * s3;
    pb[4 * LP1] = 0.5f * s4;
    pb[5 * LP1] = 0.5f * s5;
  }
}

// ---------------- Kernel 2: tropical max-plus conv2 (K=3) + avgpool2 ----------------
// w2 read wave-uniformly from global (288 values, L1/scalar). x tile in LDS.
#define T2 256
#define XT2 516

__global__ __launch_bounds__(256) void k_conv2(const float* __restrict__ p1,
                                               const float* __restrict__ w2,
                                               float* __restrict__ p2) {
  __shared__ float ps[O1][XT2];
  const int b    = blockIdx.x >> 3;
  const int tile = blockIdx.x & 7;
  const int j0   = tile * T2;
  const int tid  = threadIdx.x;

  for (int idx = tid; idx < O1 * XT2; idx += 256) {
    int c = idx / XT2;
    int p = idx - c * XT2;
    int t = 2 * j0 + p;
    ps[c][p] = (t < LP1) ? p1[((size_t)b * O1 + c) * LP1 + t] : 0.f;
  }
  __syncthreads();

  const int j = j0 + tid;
  if (j >= LP2) return;
  const int lb = 2 * tid;
  float xv[O1][4];
#pragma unroll
  for (int c = 0; c < O1; ++c) {
    xv[c][0] = ps[c][lb];     xv[c][1] = ps[c][lb + 1];
    xv[c][2] = ps[c][lb + 2]; xv[c][3] = ps[c][lb + 3];
  }
#pragma unroll
  for (int o = 0; o < O2; ++o) {
    float s = 0.f;
#pragma unroll
    for (int c = 0; c < O1; ++c) {
      float w0  = w2[(o * O1 + c) * KK2 + 0];
      float w1v = w2[(o * O1 + c) * KK2 + 1];
      float w2v = w2[(o * O1 + c) * KK2 + 2];
      float m0 = fmaxf(fmaxf(xv[c][0] + w0, xv[c][1] + w1v), xv[c][2] + w2v);
      float m1 = fmaxf(fmaxf(xv[c][1] + w0, xv[c][2] + w1v), xv[c][3] + w2v);
      s += m0 + m1;
    }
    p2[(size_t)b * NFLAT + o * LP2 + j] = 0.5f * s;
  }
}

// ---------------- Kernel 3: FC1 split-K, no LDS ----------------
// 169 chunks of 192 k. Block 512 = 16 bq x 32 it; per-thread tile 4b x 4i.
// Operands straight from global (L1 serves lane-dup), explicit prefetch.
#define KC 192
#define NKC 169        // 169*192 = 32448 exactly

__global__ __launch_bounds__(512) void k_fc1(const float* __restrict__ p2,
                                             const float* __restrict__ w,
                                             float* __restrict__ part) {
  const int kc  = blockIdx.x;
  const int k0  = kc * KC;
  const int tid = threadIdx.x;
  const int bq  = tid & 15;
  const int it  = tid >> 4;          // 0..31

  const float* xp[4];
  const float* wp[4];
  int im[4];
#pragma unroll
  for (int u = 0; u < 4; ++u) xp[u] = p2 + (size_t)(bq * 4 + u) * NFLAT + k0;
#pragma unroll
  for (int m = 0; m < 4; ++m) {
    im[m] = it + 32 * m;
    int row = im[m] < H1 ? im[m] : (H1 - 1);   // clamp OOB rows (masked at store)
    wp[m] = w + (size_t)row * NFLAT + k0;
  }

  float acc[4][4];
#pragma unroll
  for (int u = 0; u < 4; ++u)
#pragma unroll
    for (int m = 0; m < 4; ++m) acc[u][m] = 0.f;

  float4 xv[4], wv[4], xn[4], wn[4];
#pragma unroll
  for (int u = 0; u < 4; ++u) xv[u] = *(const float4*)(xp[u]);
#pragma unroll
  for (int m = 0; m < 4; ++m) wv[m] = *(const float4*)(wp[m]);

  for (int s = 0; s < KC / 4; ++s) {
    if (s + 1 < KC / 4) {
#pragma unroll
      for (int u = 0; u < 4; ++u) xn[u] = *(const float4*)(xp[u] + 4 * (s + 1));
#pragma unroll
      for (int m = 0; m < 4; ++m) wn[m] = *(const float4*)(wp[m] + 4 * (s + 1));
    }
#pragma unroll
    for (int u = 0; u < 4; ++u)
#pragma unroll
      for (int m = 0; m < 4; ++m) {
        float a = acc[u][m];
        a = fmaf(xv[u].x, wv[m].x, a);
        a = fmaf(xv[u].y, wv[m].y, a);
        a = fmaf(xv[u].z, wv[m].z, a);
        a = fmaf(xv[u].w, wv[m].w, a);
        acc[u][m] = a;
      }
#pragma unroll
    for (int u = 0; u < 4; ++u) xv[u] = xn[u];
#pragma unroll
    for (int m = 0; m < 4; ++m) wv[m] = wn[m];
  }

#pragma unroll
  for (int m = 0; m < 4; ++m) {
    if (im[m] < H1) {
      float4 v = make_float4(acc[0][m], acc[1][m], acc[2][m], acc[3][m]);
      *(float4*)&part[(size_t)kc * (H1 * BB) + im[m] * BB + bq * 4] = v;
    }
  }
}

// ---------------- Kernel 3b: reduce partials -> h1 [i][b] ----------------
__global__ __launch_bounds__(256) void k_fc1red(const float* __restrict__ part,
                                                float* __restrict__ h1) {
  const int lin = blockIdx.x * 256 + threadIdx.x;
  if (lin >= H1 * BB) return;
  float s = 0.f;
  for (int kc = 0; kc < NKC; ++kc) s += part[(size_t)kc * (H1 * BB) + lin];
  h1[lin] = s;
}

// ---------------- Kernel 4: bias+ReLU, FC2+ReLU, FC3 ----------------
__global__ __launch_bounds__(128) void k_head(const float* __restrict__ h1,
                                              const float* __restrict__ fc1_b,
                                              const float* __restrict__ fc2_w,
                                              const float* __restrict__ fc2_b,
                                              const float* __restrict__ fc3_w,
                                              const float* __restrict__ fc3_b,
                                              float* __restrict__ out) {
  __shared__ float h1s[H1];
  __shared__ float h2s[H2];
  const int b = blockIdx.x;
  const int tid = threadIdx.x;
  if (tid < H1) h1s[tid] = fmaxf(h1[tid * BB + b] + fc1_b[tid], 0.f);
  __syncthreads();
  if (tid < H2) {
    float s = fc2_b[tid];
#pragma unroll 4
    for (int n = 0; n < H1; ++n) s += h1s[n] * fc2_w[tid * H1 + n];
    h2s[tid] = fmaxf(s, 0.f);
  }
  __syncthreads();
  if (tid < NOUT) {
    float s = fc3_b[tid];
#pragma unroll 4
    for (int n = 0; n < H2; ++n) s += h2s[n] * fc3_w[tid * H2 + n];
    out[b * NOUT + tid] = s;
  }
}

extern "C" void kernel_launch(void* const* d_in, const int* in_sizes, int n_in,
                              void* d_out, int out_size, void* d_ws, size_t ws_size,
                              hipStream_t stream) {
  const float* x     = (const float*)d_in[0];
  const float* w1    = (const float*)d_in[1];
  const float* w2    = (const float*)d_in[2];
  const float* fc1_w = (const float*)d_in[3];
  const float* fc1_b = (const float*)d_in[4];
  const float* fc2_w = (const float*)d_in[5];
  const float* fc2_b = (const float*)d_in[6];
  const float* fc3_w = (const float*)d_in[7];
  const float* fc3_b = (const float*)d_in[8];

  float* ws   = (float*)d_ws;
  float* p1   = ws;                                   // 64*6*4058
  float* p2   = p1 + (size_t)BB * O1 * LP1;           // 64*32448
  float* part = p2 + (size_t)BB * NFLAT;              // 169*120*64
  float* h1   = part + (size_t)NKC * H1 * BB;         // 120*64
  float* out  = (float*)d_out;

  hipLaunchKernelGGL(k_conv1, dim3(BB * NT1), dim3(256), 0, stream, x, w1, p1);
  hipLaunchKernelGGL(k_conv2, dim3(BB * 8), dim3(256), 0, stream, p1, w2, p2);
  hipLaunchKernelGGL(k_fc1, dim3(NKC), dim3(512), 0, stream, p2, fc1_w, part);
  hipLaunchKernelGGL(k_fc1red, dim3((H1 * BB + 255) / 256), dim3(256), 0, stream, part, h1);
  hipLaunchKernelGGL(k_head, dim3(BB), dim3(128), 0, stream, h1, fc1_b, fc2_w, fc2_b,
                     fc3_w, fc3_b, out);
}

// Round 3
// 186.042 us; speedup vs baseline: 1.0613x; 1.0460x over previous
//
#include <hip/hip_runtime.h>

#define BB 64
#define C1 3
#define LIN 8192
#define PAD1 2
#define O1 6
#define KK1 80
#define LP1 4058       // pooled length after conv1(pad=2,K=80) + avgpool2

#define O2 16
#define KK2 3
#define LP2 2028

#define NFLAT 32448    // 16*2028
#define H1 120
#define H2 84
#define NOUT 10

typedef _Float16 h2 __attribute__((ext_vector_type(2)));
#define BIGH ((_Float16)30000.0f)

// ---------------- Kernel 0: pack w1 into half2 pairs (w[2m], w[2m+1]) ----------------
__global__ __launch_bounds__(256) void k_prep(const float* __restrict__ w1,
                                              float* __restrict__ whb) {
  const int idx = threadIdx.x + blockIdx.x * 256;
  if (idx >= (O1 * C1) * (KK1 / 2)) return;
  const int oc = idx / (KK1 / 2);
  const int m  = idx - oc * (KK1 / 2);
  h2 v;
  v.x = (_Float16)w1[oc * KK1 + 2 * m];
  v.y = (_Float16)w1[oc * KK1 + 2 * m + 1];
  whb[idx] = __builtin_bit_cast(float, v);
}

// ---------------- Kernel 1: tropical min-plus conv1 + avgpool2, packed fp16 ----------------
// Per pooled output j, compute conv at t=2j (accA) and t=2j+1 (accB).
// LDS holds interleaved dwords: AB[c][2d] = (xpad[T0+2d], xpad[T0+2d+1]),
//                               AB[c][2d+1] = (xpad[T0+2d+1], xpad[T0+2d+2])
// so each m-step is one 8B LDS read feeding both outputs; weights come from
// whb via wave-uniform s_load. v_pk_add_f16 + v_pk_min_f16 = 2 tropical ops/instr.
#define TJ1 256
#define NT1 16
#define DW1 298

__global__ __launch_bounds__(256) void k_conv1(const float* __restrict__ x,
                                               const float* __restrict__ whb,
                                               float* __restrict__ p1) {
  __shared__ float AB[C1][2 * DW1 + 2];
  const int b    = blockIdx.x >> 4;
  const int tile = blockIdx.x & 15;
  const int j0   = tile * TJ1;
  const int T0   = 2 * j0;            // padded-coord origin of this tile
  const int tid  = threadIdx.x;

  for (int q = tid; q < C1 * DW1; q += 256) {
    const int c = q / DW1;
    const int d = q - c * DW1;
    const int E = T0 + 2 * d - PAD1;  // x-index of element pair start
    const float* xc = x + ((size_t)b * C1 + c) * LIN;
    float f0 = 0.f, f1 = 0.f, f2 = 0.f;
    if ((unsigned)E < LIN) f0 = xc[E];
    if ((unsigned)(E + 1) < LIN) f1 = xc[E + 1];
    if ((unsigned)(E + 2) < LIN) f2 = xc[E + 2];
    h2 A; A.x = (_Float16)f0; A.y = (_Float16)f1;
    h2 Bv; Bv.x = (_Float16)f1; Bv.y = (_Float16)f2;
    AB[c][2 * d]     = __builtin_bit_cast(float, A);
    AB[c][2 * d + 1] = __builtin_bit_cast(float, Bv);
  }
  __syncthreads();

  const int jj = tid;
  const int j  = j0 + jj;

  float s0 = 0.f, s1 = 0.f, s2 = 0.f, s3 = 0.f, s4 = 0.f, s5 = 0.f;

#pragma unroll
  for (int c = 0; c < C1; ++c) {
    h2 aA[O1], aB[O1];
#pragma unroll
    for (int o = 0; o < O1; ++o) {
      aA[o].x = BIGH; aA[o].y = BIGH;
      aB[o].x = BIGH; aB[o].y = BIGH;
    }
#pragma unroll 4
    for (int m = 0; m < KK1 / 2; ++m) {
      float2 v = *(const float2*)&AB[c][2 * (jj + m)];
      h2 Ad = __builtin_bit_cast(h2, v.x);
      h2 Bd = __builtin_bit_cast(h2, v.y);
#pragma unroll
      for (int o = 0; o < O1; ++o) {
        h2 W = __builtin_bit_cast(h2, whb[(o * C1 + c) * (KK1 / 2) + m]);
        aA[o] = __builtin_elementwise_min(aA[o], Ad + W);
        aB[o] = __builtin_elementwise_min(aB[o], Bd + W);
      }
    }
    float r[O1];
#pragma unroll
    for (int o = 0; o < O1; ++o)
      r[o] = fminf((float)aA[o].x, (float)aA[o].y) + fminf((float)aB[o].x, (float)aB[o].y);
    s0 += r[0]; s1 += r[1]; s2 += r[2]; s3 += r[3]; s4 += r[4]; s5 += r[5];
  }
  if (j < LP1) {
    float* pb = p1 + (size_t)b * O1 * LP1 + j;
    pb[0 * LP1] = 0.5f * s0;
    pb[1 * LP1] = 0.5f * s1;
    pb[2 * LP1] = 0.5f * s2;
    pb[3 * LP1] = 0.5f * s3;
    pb[4 * LP1] = 0.5f * s4;
    pb[5 * LP1] = 0.5f * s5;
  }
}

// ---------------- Kernel 2: tropical max-plus conv2 (K=3) + avgpool2 ----------------
#define T2 256
#define XT2 516

__global__ __launch_bounds__(256) void k_conv2(const float* __restrict__ p1,
                                               const float* __restrict__ w2,
                                               float* __restrict__ p2) {
  __shared__ float ps[O1][XT2];
  const int b    = blockIdx.x >> 3;
  const int tile = blockIdx.x & 7;
  const int j0   = tile * T2;
  const int tid  = threadIdx.x;

  for (int idx = tid; idx < O1 * XT2; idx += 256) {
    int c = idx / XT2;
    int p = idx - c * XT2;
    int t = 2 * j0 + p;
    ps[c][p] = (t < LP1) ? p1[((size_t)b * O1 + c) * LP1 + t] : 0.f;
  }
  __syncthreads();

  const int j = j0 + tid;
  if (j >= LP2) return;
  const int lb = 2 * tid;
  float xv[O1][4];
#pragma unroll
  for (int c = 0; c < O1; ++c) {
    xv[c][0] = ps[c][lb];     xv[c][1] = ps[c][lb + 1];
    xv[c][2] = ps[c][lb + 2]; xv[c][3] = ps[c][lb + 3];
  }
#pragma unroll
  for (int o = 0; o < O2; ++o) {
    float s = 0.f;
#pragma unroll
    for (int c = 0; c < O1; ++c) {
      float w0  = w2[(o * O1 + c) * KK2 + 0];
      float w1v = w2[(o * O1 + c) * KK2 + 1];
      float w2v = w2[(o * O1 + c) * KK2 + 2];
      float m0 = fmaxf(fmaxf(xv[c][0] + w0, xv[c][1] + w1v), xv[c][2] + w2v);
      float m1 = fmaxf(fmaxf(xv[c][1] + w0, xv[c][2] + w1v), xv[c][3] + w2v);
      s += m0 + m1;
    }
    p2[(size_t)b * NFLAT + o * LP2 + j] = 0.5f * s;
  }
}

// ---------------- Kernel 3: FC1 split-K — lanes=batch, SGPR weights ----------------
// Grid 508 = 254 K-chunks x 2 i-halves. Block 256 = 4 waves; lane = b (64).
// x chunk staged in LDS [64][132] (conflict-free b128); each wave owns 15 i
// (groups of 8+7); w addresses wave-uniform -> s_load_dwordx4, FMA vgpr x sgpr.
#define KC 128
#define NKC 254

template<int G>
__device__ __forceinline__ void fc1_group(const float* __restrict__ w,
                                          const float* xs_lane,
                                          int i0, int k0,
                                          float* __restrict__ part_out, int lane) {
  float acc[G];
#pragma unroll
  for (int g = 0; g < G; ++g) acc[g] = 0.f;
  const float* wb[G];
#pragma unroll
  for (int g = 0; g < G; ++g) wb[g] = w + (size_t)(i0 + g) * NFLAT;

  for (int k4 = 0; k4 < KC; k4 += 4) {
    int wk = k0 + k4;
    if (wk >= NFLAT) wk = 0;              // tail: xv is zero there anyway
    float4 xv = *(const float4*)(xs_lane + k4);
#pragma unroll
    for (int g = 0; g < G; ++g) {
      float4 wv = *(const float4*)(wb[g] + wk);
      float a = acc[g];
      a = fmaf(xv.x, wv.x, a);
      a = fmaf(xv.y, wv.y, a);
      a = fmaf(xv.z, wv.z, a);
      a = fmaf(xv.w, wv.w, a);
      acc[g] = a;
    }
  }
#pragma unroll
  for (int g = 0; g < G; ++g) part_out[(i0 + g) * BB + lane] = acc[g];
}

__global__ __launch_bounds__(256) void k_fc1(const float* __restrict__ p2,
                                             const float* __restrict__ w,
                                             float* __restrict__ part) {
  __shared__ float xs[BB * 132];
  const int kc   = blockIdx.x >> 1;
  const int half = blockIdx.x & 1;
  const int k0   = kc * KC;
  const int tid  = threadIdx.x;

  // stage x chunk: 64 rows x 128 k, coalesced float4
  for (int it = 0; it < 8; ++it) {
    const int g  = tid + 256 * it;       // 0..2047
    const int row = g >> 5;
    const int c4  = g & 31;
    const int k   = k0 + c4 * 4;
    float4 v = make_float4(0.f, 0.f, 0.f, 0.f);
    if (k < NFLAT) v = *(const float4*)&p2[(size_t)row * NFLAT + k];
    *(float4*)&xs[row * 132 + c4 * 4] = v;
  }
  __syncthreads();

  const int lane = tid & 63;
  const int wid  = __builtin_amdgcn_readfirstlane(tid >> 6);
  const int i0   = half * 60 + wid * 15;
  const float* xs_lane = &xs[lane * 132];
  float* pout = part + (size_t)kc * (H1 * BB);

  fc1_group<8>(w, xs_lane, i0, k0, pout, lane);
  fc1_group<7>(w, xs_lane, i0 + 8, k0, pout, lane);
}

// ---------------- Kernel 3b: reduce partials -> h1 [i][b] ----------------
__global__ __launch_bounds__(256) void k_fc1red(const float* __restrict__ part,
                                                float* __restrict__ h1) {
  __shared__ float red[256];
  const int i   = blockIdx.x;            // 0..119
  const int tid = threadIdx.x;
  const int b   = tid & 63;
  const int s   = tid >> 6;
  float acc = 0.f;
  for (int kc = s; kc < NKC; kc += 4)
    acc += part[(size_t)kc * (H1 * BB) + i * BB + b];
  red[tid] = acc;
  __syncthreads();
  if (tid < 64)
    h1[i * BB + b] = red[b] + red[b + 64] + red[b + 128] + red[b + 192];
}

// ---------------- Kernel 4: bias+ReLU, FC2+ReLU, FC3 ----------------
__global__ __launch_bounds__(128) void k_head(const float* __restrict__ h1,
                                              const float* __restrict__ fc1_b,
                                              const float* __restrict__ fc2_w,
                                              const float* __restrict__ fc2_b,
                                              const float* __restrict__ fc3_w,
                                              const float* __restrict__ fc3_b,
                                              float* __restrict__ out) {
  __shared__ float h1s[H1];
  __shared__ float h2s[H2];
  const int b = blockIdx.x;
  const int tid = threadIdx.x;
  if (tid < H1) h1s[tid] = fmaxf(h1[tid * BB + b] + fc1_b[tid], 0.f);
  __syncthreads();
  if (tid < H2) {
    float s = fc2_b[tid];
#pragma unroll 4
    for (int n = 0; n < H1; ++n) s += h1s[n] * fc2_w[tid * H1 + n];
    h2s[tid] = fmaxf(s, 0.f);
  }
  __syncthreads();
  if (tid < NOUT) {
    float s = fc3_b[tid];
#pragma unroll 4
    for (int n = 0; n < H2; ++n) s += h2s[n] * fc3_w[tid * H2 + n];
    out[b * NOUT + tid] = s;
  }
}

extern "C" void kernel_launch(void* const* d_in, const int* in_sizes, int n_in,
                              void* d_out, int out_size, void* d_ws, size_t ws_size,
                              hipStream_t stream) {
  const float* x     = (const float*)d_in[0];
  const float* w1    = (const float*)d_in[1];
  const float* w2    = (const float*)d_in[2];
  const float* fc1_w = (const float*)d_in[3];
  const float* fc1_b = (const float*)d_in[4];
  const float* fc2_w = (const float*)d_in[5];
  const float* fc2_b = (const float*)d_in[6];
  const float* fc3_w = (const float*)d_in[7];
  const float* fc3_b = (const float*)d_in[8];

  float* ws   = (float*)d_ws;
  float* p1   = ws;                                   // 64*6*4058
  float* p2   = p1 + (size_t)BB * O1 * LP1;           // 64*32448
  float* part = p2 + (size_t)BB * NFLAT;              // 254*120*64
  float* h1   = part + (size_t)NKC * H1 * BB;         // 120*64
  float* whb  = h1 + (size_t)H1 * BB;                 // 720
  float* out  = (float*)d_out;

  hipLaunchKernelGGL(k_prep, dim3(3), dim3(256), 0, stream, w1, whb);
  hipLaunchKernelGGL(k_conv1, dim3(BB * NT1), dim3(256), 0, stream, x, whb, p1);
  hipLaunchKernelGGL(k_conv2, dim3(BB * 8), dim3(256), 0, stream, p1, w2, p2);
  hipLaunchKernelGGL(k_fc1, dim3(2 * NKC), dim3(256), 0, stream, p2, fc1_w, part);
  hipLaunchKernelGGL(k_fc1red, dim3(H1), dim3(256), 0, stream, part, h1);
  hipLaunchKernelGGL(k_head, dim3(BB), dim3(128), 0, stream, h1, fc1_b, fc2_w, fc2_b,
                     fc3_w, fc3_b, out);
}

// Round 4
// 177.489 us; speedup vs baseline: 1.1125x; 1.0482x over previous
//
#include <hip/hip_runtime.h>

#define BB 64
#define C1 3
#define LIN 8192
#define PAD1 2
#define O1 6
#define KK1 80
#define LP1 4058       // pooled length after conv1(pad=2,K=80) + avgpool2

#define O2 16
#define KK2 3
#define LP2 2028

#define NFLAT 32448    // 16*2028
#define H1 120
#define H2 84
#define NOUT 10

typedef _Float16 h2 __attribute__((ext_vector_type(2)));
#define BIGH ((_Float16)30000.0f)

// ---------------- Kernel 0: pack w1 into half2 pairs (w[2m], w[2m+1]) ----------------
__global__ __launch_bounds__(256) void k_prep(const float* __restrict__ w1,
                                              float* __restrict__ whb) {
  const int idx = threadIdx.x + blockIdx.x * 256;
  if (idx >= (O1 * C1) * (KK1 / 2)) return;
  const int oc = idx / (KK1 / 2);
  const int m  = idx - oc * (KK1 / 2);
  h2 v;
  v.x = (_Float16)w1[oc * KK1 + 2 * m];
  v.y = (_Float16)w1[oc * KK1 + 2 * m + 1];
  whb[idx] = __builtin_bit_cast(float, v);
}

// ---------------- Kernel 1: tropical min-plus conv1 + avgpool2, packed fp16 ----------------
#define TJ1 256
#define NT1 16
#define DW1 298

__global__ __launch_bounds__(256) void k_conv1(const float* __restrict__ x,
                                               const float* __restrict__ whb,
                                               float* __restrict__ p1) {
  __shared__ float AB[C1][2 * DW1 + 2];
  const int b    = blockIdx.x >> 4;
  const int tile = blockIdx.x & 15;
  const int j0   = tile * TJ1;
  const int T0   = 2 * j0;            // padded-coord origin of this tile
  const int tid  = threadIdx.x;

  for (int q = tid; q < C1 * DW1; q += 256) {
    const int c = q / DW1;
    const int d = q - c * DW1;
    const int E = T0 + 2 * d - PAD1;  // x-index of element pair start
    const float* xc = x + ((size_t)b * C1 + c) * LIN;
    float f0 = 0.f, f1 = 0.f, f2 = 0.f;
    if ((unsigned)E < LIN) f0 = xc[E];
    if ((unsigned)(E + 1) < LIN) f1 = xc[E + 1];
    if ((unsigned)(E + 2) < LIN) f2 = xc[E + 2];
    h2 A; A.x = (_Float16)f0; A.y = (_Float16)f1;
    h2 Bv; Bv.x = (_Float16)f1; Bv.y = (_Float16)f2;
    AB[c][2 * d]     = __builtin_bit_cast(float, A);
    AB[c][2 * d + 1] = __builtin_bit_cast(float, Bv);
  }
  __syncthreads();

  const int jj = tid;
  const int j  = j0 + jj;

  float s0 = 0.f, s1 = 0.f, s2 = 0.f, s3 = 0.f, s4 = 0.f, s5 = 0.f;

#pragma unroll
  for (int c = 0; c < C1; ++c) {
    h2 aA[O1], aB[O1];
#pragma unroll
    for (int o = 0; o < O1; ++o) {
      aA[o].x = BIGH; aA[o].y = BIGH;
      aB[o].x = BIGH; aB[o].y = BIGH;
    }
#pragma unroll 4
    for (int m = 0; m < KK1 / 2; ++m) {
      float2 v = *(const float2*)&AB[c][2 * (jj + m)];
      h2 Ad = __builtin_bit_cast(h2, v.x);
      h2 Bd = __builtin_bit_cast(h2, v.y);
#pragma unroll
      for (int o = 0; o < O1; ++o) {
        h2 W = __builtin_bit_cast(h2, whb[(o * C1 + c) * (KK1 / 2) + m]);
        aA[o] = __builtin_elementwise_min(aA[o], Ad + W);
        aB[o] = __builtin_elementwise_min(aB[o], Bd + W);
      }
    }
    float r[O1];
#pragma unroll
    for (int o = 0; o < O1; ++o)
      r[o] = fminf((float)aA[o].x, (float)aA[o].y) + fminf((float)aB[o].x, (float)aB[o].y);
    s0 += r[0]; s1 += r[1]; s2 += r[2]; s3 += r[3]; s4 += r[4]; s5 += r[5];
  }
  if (j < LP1) {
    float* pb = p1 + (size_t)b * O1 * LP1 + j;
    pb[0 * LP1] = 0.5f * s0;
    pb[1 * LP1] = 0.5f * s1;
    pb[2 * LP1] = 0.5f * s2;
    pb[3 * LP1] = 0.5f * s3;
    pb[4 * LP1] = 0.5f * s4;
    pb[5 * LP1] = 0.5f * s5;
  }
}

// ---------------- Kernel 2: tropical max-plus conv2 (K=3) + avgpool2 ----------------
#define T2 256
#define XT2 516

__global__ __launch_bounds__(256) void k_conv2(const float* __restrict__ p1,
                                               const float* __restrict__ w2,
                                               float* __restrict__ p2) {
  __shared__ float ps[O1][XT2];
  const int b    = blockIdx.x >> 3;
  const int tile = blockIdx.x & 7;
  const int j0   = tile * T2;
  const int tid  = threadIdx.x;

  for (int idx = tid; idx < O1 * XT2; idx += 256) {
    int c = idx / XT2;
    int p = idx - c * XT2;
    int t = 2 * j0 + p;
    ps[c][p] = (t < LP1) ? p1[((size_t)b * O1 + c) * LP1 + t] : 0.f;
  }
  __syncthreads();

  const int j = j0 + tid;
  if (j >= LP2) return;
  const int lb = 2 * tid;
  float xv[O1][4];
#pragma unroll
  for (int c = 0; c < O1; ++c) {
    xv[c][0] = ps[c][lb];     xv[c][1] = ps[c][lb + 1];
    xv[c][2] = ps[c][lb + 2]; xv[c][3] = ps[c][lb + 3];
  }
#pragma unroll
  for (int o = 0; o < O2; ++o) {
    float s = 0.f;
#pragma unroll
    for (int c = 0; c < O1; ++c) {
      float w0  = w2[(o * O1 + c) * KK2 + 0];
      float w1v = w2[(o * O1 + c) * KK2 + 1];
      float w2v = w2[(o * O1 + c) * KK2 + 2];
      float m0 = fmaxf(fmaxf(xv[c][0] + w0, xv[c][1] + w1v), xv[c][2] + w2v);
      float m1 = fmaxf(fmaxf(xv[c][1] + w0, xv[c][2] + w1v), xv[c][3] + w2v);
      s += m0 + m1;
    }
    p2[(size_t)b * NFLAT + o * LP2 + j] = 0.5f * s;
  }
}

// ---------------- Kernel 3: FC1 split-K v4 ----------------
// Grid 508 = 254 kc x 2 i-halves; block 512 = 8 waves; lane = b.
// x: LDS transposed k-major xs[128][67] -> conflict-free b32 compute reads.
// w: per-wave BROADCAST global dwordx4 (uniform addr, NOT scalarized ->
//    vmcnt-ordered, compiler pipelines). 32 FMA per 8 VMEM + 4 LDS per k4.
#define KC 128
#define NKC 254

__global__ __launch_bounds__(512) void k_fc1(const float* __restrict__ p2,
                                             const float* __restrict__ w,
                                             float* __restrict__ part) {
  __shared__ float xs[KC][67];
  const int kc  = blockIdx.x >> 1;
  const int ih  = blockIdx.x & 1;
  const int k0  = kc * KC;
  const int tid = threadIdx.x;

  // stage x chunk transposed: 64 rows x 128 k
#pragma unroll
  for (int r = 0; r < 4; ++r) {
    const int idx = tid + 512 * r;
    const int row = idx >> 5;          // 0..63
    const int c4  = idx & 31;
    const int k   = k0 + c4 * 4;
    float4 v = make_float4(0.f, 0.f, 0.f, 0.f);
    if (k < NFLAT) v = *(const float4*)&p2[(size_t)row * NFLAT + k];
    xs[c4 * 4 + 0][row] = v.x;
    xs[c4 * 4 + 1][row] = v.y;
    xs[c4 * 4 + 2][row] = v.z;
    xs[c4 * 4 + 3][row] = v.w;
  }
  __syncthreads();

  const int lane = tid & 63;
  const int wv   = tid >> 6;           // 0..7 (NOT readfirstlane'd: keep VMEM path)
  const int i0   = ih * 64 + wv * 8;

  const float* wb[8];
#pragma unroll
  for (int g = 0; g < 8; ++g) {
    int row = i0 + g; if (row >= H1) row = H1 - 1;
    wb[g] = w + (size_t)row * NFLAT;
  }

  float acc[8];
#pragma unroll
  for (int g = 0; g < 8; ++g) acc[g] = 0.f;

#pragma unroll 4
  for (int k4 = 0; k4 < KC / 4; ++k4) {
    int kk = k0 + k4 * 4;
    if (kk + 4 > NFLAT) kk = 0;        // uniform; x is zero there anyway
    float x0 = xs[k4 * 4 + 0][lane];
    float x1 = xs[k4 * 4 + 1][lane];
    float x2 = xs[k4 * 4 + 2][lane];
    float x3 = xs[k4 * 4 + 3][lane];
#pragma unroll
    for (int g = 0; g < 8; ++g) {
      float4 wv4 = *(const float4*)(wb[g] + kk);
      float a = acc[g];
      a = fmaf(x0, wv4.x, a);
      a = fmaf(x1, wv4.y, a);
      a = fmaf(x2, wv4.z, a);
      a = fmaf(x3, wv4.w, a);
      acc[g] = a;
    }
  }

#pragma unroll
  for (int g = 0; g < 8; ++g) {
    const int i = i0 + g;
    if (i < H1) part[((size_t)kc * 128 + i) * 64 + lane] = acc[g];
  }
}

// ---------------- Kernel 3b: reduce partials -> h1 [i][b] ----------------
__global__ __launch_bounds__(512) void k_fc1red(const float* __restrict__ part,
                                                float* __restrict__ h1) {
  __shared__ float red[512];
  const int i   = blockIdx.x;            // 0..119
  const int tid = threadIdx.x;
  const int b   = tid & 63;
  const int s   = tid >> 6;              // 0..7
  float acc = 0.f;
  for (int kc = s; kc < NKC; kc += 8)
    acc += part[((size_t)kc * 128 + i) * 64 + b];
  red[tid] = acc;
  __syncthreads();
  if (tid < 64) {
    float t = 0.f;
#pragma unroll
    for (int s2 = 0; s2 < 8; ++s2) t += red[b + 64 * s2];
    h1[i * BB + b] = t;
  }
}

// ---------------- Kernel 4: bias+ReLU, FC2+ReLU, FC3 ----------------
__global__ __launch_bounds__(128) void k_head(const float* __restrict__ h1,
                                              const float* __restrict__ fc1_b,
                                              const float* __restrict__ fc2_w,
                                              const float* __restrict__ fc2_b,
                                              const float* __restrict__ fc3_w,
                                              const float* __restrict__ fc3_b,
                                              float* __restrict__ out) {
  __shared__ float h1s[H1];
  __shared__ float h2s[H2];
  const int b = blockIdx.x;
  const int tid = threadIdx.x;
  if (tid < H1) h1s[tid] = fmaxf(h1[tid * BB + b] + fc1_b[tid], 0.f);
  __syncthreads();
  if (tid < H2) {
    float s = fc2_b[tid];
#pragma unroll 4
    for (int n = 0; n < H1; ++n) s += h1s[n] * fc2_w[tid * H1 + n];
    h2s[tid] = fmaxf(s, 0.f);
  }
  __syncthreads();
  if (tid < NOUT) {
    float s = fc3_b[tid];
#pragma unroll 4
    for (int n = 0; n < H2; ++n) s += h2s[n] * fc3_w[tid * H2 + n];
    out[b * NOUT + tid] = s;
  }
}

extern "C" void kernel_launch(void* const* d_in, const int* in_sizes, int n_in,
                              void* d_out, int out_size, void* d_ws, size_t ws_size,
                              hipStream_t stream) {
  const float* x     = (const float*)d_in[0];
  const float* w1    = (const float*)d_in[1];
  const float* w2    = (const float*)d_in[2];
  const float* fc1_w = (const float*)d_in[3];
  const float* fc1_b = (const float*)d_in[4];
  const float* fc2_w = (const float*)d_in[5];
  const float* fc2_b = (const float*)d_in[6];
  const float* fc3_w = (const float*)d_in[7];
  const float* fc3_b = (const float*)d_in[8];

  float* ws   = (float*)d_ws;
  float* p1   = ws;                                   // 64*6*4058
  float* p2   = p1 + (size_t)BB * O1 * LP1;           // 64*32448
  float* part = p2 + (size_t)BB * NFLAT;              // 254*128*64
  float* h1   = part + (size_t)NKC * 128 * BB;        // 120*64
  float* whb  = h1 + (size_t)H1 * BB;                 // 720
  float* out  = (float*)d_out;

  hipLaunchKernelGGL(k_prep, dim3(3), dim3(256), 0, stream, w1, whb);
  hipLaunchKernelGGL(k_conv1, dim3(BB * NT1), dim3(256), 0, stream, x, whb, p1);
  hipLaunchKernelGGL(k_conv2, dim3(BB * 8), dim3(256), 0, stream, p1, w2, p2);
  hipLaunchKernelGGL(k_fc1, dim3(2 * NKC), dim3(512), 0, stream, p2, fc1_w, part);
  hipLaunchKernelGGL(k_fc1red, dim3(H1), dim3(512), 0, stream, part, h1);
  hipLaunchKernelGGL(k_head, dim3(BB), dim3(128), 0, stream, h1, fc1_b, fc2_w, fc2_b,
                     fc3_w, fc3_b, out);
}

// Round 5
// 143.976 us; speedup vs baseline: 1.3714x; 1.2328x over previous
//
#include <hip/hip_runtime.h>

#define BB 64
#define C1 3
#define LIN 8192
#define PAD1 2
#define O1 6
#define KK1 80
#define LP1 4058       // pooled length after conv1(pad=2,K=80) + avgpool2

#define O2 16
#define KK2 3
#define LP2 2028

#define NFLAT 32448    // 16*2028 = 507*64
#define H1 120
#define H2 84
#define NOUT 10

typedef _Float16 h2 __attribute__((ext_vector_type(2)));
typedef _Float16 f16x8 __attribute__((ext_vector_type(8)));
typedef float f32x4 __attribute__((ext_vector_type(4)));
#define BIGH ((_Float16)30000.0f)

// ---------------- Kernel 0: pack w1 into half2 pairs (w[2m], w[2m+1]) ----------------
__global__ __launch_bounds__(256) void k_prep(const float* __restrict__ w1,
                                              float* __restrict__ whb) {
  const int idx = threadIdx.x + blockIdx.x * 256;
  if (idx >= (O1 * C1) * (KK1 / 2)) return;
  const int oc = idx / (KK1 / 2);
  const int m  = idx - oc * (KK1 / 2);
  h2 v;
  v.x = (_Float16)w1[oc * KK1 + 2 * m];
  v.y = (_Float16)w1[oc * KK1 + 2 * m + 1];
  whb[idx] = __builtin_bit_cast(float, v);
}

// ---------------- Kernel 1: tropical min-plus conv1 + avgpool2, packed fp16 ----------------
#define TJ1 256
#define NT1 16
#define DW1 298

__global__ __launch_bounds__(256) void k_conv1(const float* __restrict__ x,
                                               const float* __restrict__ whb,
                                               float* __restrict__ p1) {
  __shared__ float AB[C1][2 * DW1 + 2];
  const int b    = blockIdx.x >> 4;
  const int tile = blockIdx.x & 15;
  const int j0   = tile * TJ1;
  const int T0   = 2 * j0;
  const int tid  = threadIdx.x;

  for (int q = tid; q < C1 * DW1; q += 256) {
    const int c = q / DW1;
    const int d = q - c * DW1;
    const int E = T0 + 2 * d - PAD1;
    const float* xc = x + ((size_t)b * C1 + c) * LIN;
    float f0 = 0.f, f1 = 0.f, f2 = 0.f;
    if ((unsigned)E < LIN) f0 = xc[E];
    if ((unsigned)(E + 1) < LIN) f1 = xc[E + 1];
    if ((unsigned)(E + 2) < LIN) f2 = xc[E + 2];
    h2 A; A.x = (_Float16)f0; A.y = (_Float16)f1;
    h2 Bv; Bv.x = (_Float16)f1; Bv.y = (_Float16)f2;
    AB[c][2 * d]     = __builtin_bit_cast(float, A);
    AB[c][2 * d + 1] = __builtin_bit_cast(float, Bv);
  }
  __syncthreads();

  const int jj = tid;
  const int j  = j0 + jj;

  float s0 = 0.f, s1 = 0.f, s2 = 0.f, s3 = 0.f, s4 = 0.f, s5 = 0.f;

#pragma unroll
  for (int c = 0; c < C1; ++c) {
    h2 aA[O1], aB[O1];
#pragma unroll
    for (int o = 0; o < O1; ++o) {
      aA[o].x = BIGH; aA[o].y = BIGH;
      aB[o].x = BIGH; aB[o].y = BIGH;
    }
#pragma unroll 4
    for (int m = 0; m < KK1 / 2; ++m) {
      float2 v = *(const float2*)&AB[c][2 * (jj + m)];
      h2 Ad = __builtin_bit_cast(h2, v.x);
      h2 Bd = __builtin_bit_cast(h2, v.y);
#pragma unroll
      for (int o = 0; o < O1; ++o) {
        h2 W = __builtin_bit_cast(h2, whb[(o * C1 + c) * (KK1 / 2) + m]);
        aA[o] = __builtin_elementwise_min(aA[o], Ad + W);
        aB[o] = __builtin_elementwise_min(aB[o], Bd + W);
      }
    }
    float r[O1];
#pragma unroll
    for (int o = 0; o < O1; ++o)
      r[o] = fminf((float)aA[o].x, (float)aA[o].y) + fminf((float)aB[o].x, (float)aB[o].y);
    s0 += r[0]; s1 += r[1]; s2 += r[2]; s3 += r[3]; s4 += r[4]; s5 += r[5];
  }
  if (j < LP1) {
    float* pb = p1 + (size_t)b * O1 * LP1 + j;
    pb[0 * LP1] = 0.5f * s0;
    pb[1 * LP1] = 0.5f * s1;
    pb[2 * LP1] = 0.5f * s2;
    pb[3 * LP1] = 0.5f * s3;
    pb[4 * LP1] = 0.5f * s4;
    pb[5 * LP1] = 0.5f * s5;
  }
}

// ---------------- Kernel 2: tropical max-plus conv2 (K=3) + avgpool2 -> f16 ----------------
#define T2 256
#define XT2 516

__global__ __launch_bounds__(256) void k_conv2(const float* __restrict__ p1,
                                               const float* __restrict__ w2,
                                               _Float16* __restrict__ p2h) {
  __shared__ float ps[O1][XT2];
  __shared__ float w2s[O2 * O1 * KK2];   // 288 floats
  const int b    = blockIdx.x >> 3;
  const int tile = blockIdx.x & 7;
  const int j0   = tile * T2;
  const int tid  = threadIdx.x;

  for (int idx = tid; idx < O2 * O1 * KK2; idx += 256) w2s[idx] = w2[idx];
  for (int idx = tid; idx < O1 * XT2; idx += 256) {
    int c = idx / XT2;
    int p = idx - c * XT2;
    int t = 2 * j0 + p;
    ps[c][p] = (t < LP1) ? p1[((size_t)b * O1 + c) * LP1 + t] : 0.f;
  }
  __syncthreads();

  const int j = j0 + tid;
  if (j >= LP2) return;
  const int lb = 2 * tid;
  float xv[O1][4];
#pragma unroll
  for (int c = 0; c < O1; ++c) {
    xv[c][0] = ps[c][lb];     xv[c][1] = ps[c][lb + 1];
    xv[c][2] = ps[c][lb + 2]; xv[c][3] = ps[c][lb + 3];
  }
#pragma unroll
  for (int o = 0; o < O2; ++o) {
    float s = 0.f;
#pragma unroll
    for (int c = 0; c < O1; ++c) {
      float w0  = w2s[(o * O1 + c) * KK2 + 0];
      float w1v = w2s[(o * O1 + c) * KK2 + 1];
      float w2v = w2s[(o * O1 + c) * KK2 + 2];
      float m0 = fmaxf(fmaxf(xv[c][0] + w0, xv[c][1] + w1v), xv[c][2] + w2v);
      float m1 = fmaxf(fmaxf(xv[c][1] + w0, xv[c][2] + w1v), xv[c][3] + w2v);
      s += m0 + m1;
    }
    p2h[(size_t)b * NFLAT + o * LP2 + j] = (_Float16)(0.5f * s);
  }
}

// ---------------- Kernel 3: FC1 split-K via MFMA f16 ----------------
// Grid 507 kc (K=64 each); block 256 = 4 waves. Wave owns M-rows [wid*32,wid*32+32)
// as 2 16-row tiles x all 4 N-tiles (N=64 batch). A = w fp32 per-lane fragment
// loads (128B segments) + cvt f16; B = p2h chunk staged to LDS (8 KB), b128 frags.
// A-layout: A[m=lane&15][k=quad*8+j]; C/D: col=lane&15(n), row=quad*4+reg(m).
#define KC2 64
#define NKC2 507

__global__ __launch_bounds__(256) void k_fc1(const _Float16* __restrict__ p2h,
                                             const float* __restrict__ w,
                                             _Float16* __restrict__ part) {
  __shared__ _Float16 bs[64][KC2];    // [b][k], 8 KB
  const int kc  = blockIdx.x;
  const int k0  = kc * KC2;
  const int tid = threadIdx.x;

  // stage B chunk: 64 rows x 64 f16 (128 B/row), dwordx4 per task
#pragma unroll
  for (int r = 0; r < 2; ++r) {
    const int task = tid + 256 * r;        // 0..511
    const int row  = task >> 3;
    const int c4   = task & 7;
    float4 v = *(const float4*)&p2h[(size_t)row * NFLAT + k0 + c4 * 8];
    *(float4*)&bs[row][c4 * 8] = v;
  }
  __syncthreads();

  const int lane = tid & 63;
  const int wid  = tid >> 6;             // 0..3
  const int m_l  = lane & 15;
  const int q    = lane >> 4;            // 0..3
  const int m0   = wid * 32;

  const int rowA0 = m0 + m_l;            // <= 111, always valid
  int rowA1 = m0 + 16 + m_l;             // <= 127; clamp pad rows
  if (rowA1 > H1 - 1) rowA1 = H1 - 1;
  const float* wp0 = w + (size_t)rowA0 * NFLAT + k0 + q * 8;
  const float* wp1 = w + (size_t)rowA1 * NFLAT + k0 + q * 8;

  f32x4 acc[2][4];
#pragma unroll
  for (int t = 0; t < 2; ++t)
#pragma unroll
    for (int nt = 0; nt < 4; ++nt) acc[t][nt] = (f32x4){0.f, 0.f, 0.f, 0.f};

#pragma unroll
  for (int ks = 0; ks < 2; ++ks) {
    float4 a0l = *(const float4*)(wp0 + ks * 32);
    float4 a0h = *(const float4*)(wp0 + ks * 32 + 4);
    float4 a1l = *(const float4*)(wp1 + ks * 32);
    float4 a1h = *(const float4*)(wp1 + ks * 32 + 4);
    f16x8 A0, A1;
    A0[0] = (_Float16)a0l.x; A0[1] = (_Float16)a0l.y;
    A0[2] = (_Float16)a0l.z; A0[3] = (_Float16)a0l.w;
    A0[4] = (_Float16)a0h.x; A0[5] = (_Float16)a0h.y;
    A0[6] = (_Float16)a0h.z; A0[7] = (_Float16)a0h.w;
    A1[0] = (_Float16)a1l.x; A1[1] = (_Float16)a1l.y;
    A1[2] = (_Float16)a1l.z; A1[3] = (_Float16)a1l.w;
    A1[4] = (_Float16)a1h.x; A1[5] = (_Float16)a1h.y;
    A1[6] = (_Float16)a1h.z; A1[7] = (_Float16)a1h.w;
#pragma unroll
    for (int nt = 0; nt < 4; ++nt) {
      f16x8 Bf = *(const f16x8*)&bs[nt * 16 + m_l][ks * 32 + q * 8];
      acc[0][nt] = __builtin_amdgcn_mfma_f32_16x16x32_f16(A0, Bf, acc[0][nt], 0, 0, 0);
      acc[1][nt] = __builtin_amdgcn_mfma_f32_16x16x32_f16(A1, Bf, acc[1][nt], 0, 0, 0);
    }
  }

  // D: row(m) = quad*4 + reg, col(n) = lane&15
#pragma unroll
  for (int t = 0; t < 2; ++t)
#pragma unroll
    for (int nt = 0; nt < 4; ++nt)
#pragma unroll
      for (int r = 0; r < 4; ++r) {
        const int i = m0 + t * 16 + q * 4 + r;
        if (i < H1)
          part[((size_t)kc * H1 + i) * 64 + nt * 16 + m_l] = (_Float16)acc[t][nt][r];
      }
}

// ---------------- Kernel 3b: reduce partials -> part2[4][120][64] f32 ----------------
__global__ __launch_bounds__(512) void k_fc1red(const _Float16* __restrict__ part,
                                                float* __restrict__ part2) {
  __shared__ float red[512];
  const int bx  = blockIdx.x;            // 0..479
  const int s   = bx / H1;               // 0..3
  const int i   = bx - s * H1;           // 0..119
  const int tid = threadIdx.x;
  const int b   = tid & 63;
  const int sub = tid >> 6;              // 0..7
  const int kc0 = s * 127;
  const int kc1 = (kc0 + 127 < NKC2) ? kc0 + 127 : NKC2;
  float acc = 0.f;
  for (int kc = kc0 + sub; kc < kc1; kc += 8)
    acc += (float)part[((size_t)kc * H1 + i) * 64 + b];
  red[tid] = acc;
  __syncthreads();
  if (tid < 64) {
    float t = 0.f;
#pragma unroll
    for (int s2 = 0; s2 < 8; ++s2) t += red[b + 64 * s2];
    part2[((size_t)s * H1 + i) * 64 + b] = t;
  }
}

// ---------------- Kernel 4: bias+ReLU, FC2+ReLU, FC3 ----------------
__global__ __launch_bounds__(128) void k_head(const float* __restrict__ part2,
                                              const float* __restrict__ fc1_b,
                                              const float* __restrict__ fc2_w,
                                              const float* __restrict__ fc2_b,
                                              const float* __restrict__ fc3_w,
                                              const float* __restrict__ fc3_b,
                                              float* __restrict__ out) {
  __shared__ float h1s[H1];
  __shared__ float h2s[H2];
  const int b = blockIdx.x;
  const int tid = threadIdx.x;
  if (tid < H1) {
    float v = part2[((size_t)0 * H1 + tid) * 64 + b]
            + part2[((size_t)1 * H1 + tid) * 64 + b]
            + part2[((size_t)2 * H1 + tid) * 64 + b]
            + part2[((size_t)3 * H1 + tid) * 64 + b];
    h1s[tid] = fmaxf(v + fc1_b[tid], 0.f);
  }
  __syncthreads();
  if (tid < H2) {
    float s = fc2_b[tid];
#pragma unroll 4
    for (int n = 0; n < H1; ++n) s += h1s[n] * fc2_w[tid * H1 + n];
    h2s[tid] = fmaxf(s, 0.f);
  }
  __syncthreads();
  if (tid < NOUT) {
    float s = fc3_b[tid];
#pragma unroll 4
    for (int n = 0; n < H2; ++n) s += h2s[n] * fc3_w[tid * H2 + n];
    out[b * NOUT + tid] = s;
  }
}

extern "C" void kernel_launch(void* const* d_in, const int* in_sizes, int n_in,
                              void* d_out, int out_size, void* d_ws, size_t ws_size,
                              hipStream_t stream) {
  const float* x     = (const float*)d_in[0];
  const float* w1    = (const float*)d_in[1];
  const float* w2    = (const float*)d_in[2];
  const float* fc1_w = (const float*)d_in[3];
  const float* fc1_b = (const float*)d_in[4];
  const float* fc2_w = (const float*)d_in[5];
  const float* fc2_b = (const float*)d_in[6];
  const float* fc3_w = (const float*)d_in[7];
  const float* fc3_b = (const float*)d_in[8];

  float* ws = (float*)d_ws;
  float*     p1    = ws;                                        // 1,558,272 f
  _Float16*  p2h   = (_Float16*)(p1 + (size_t)BB * O1 * LP1);   // 2,076,672 h
  _Float16*  part  = p2h + (size_t)BB * NFLAT;                  // 507*120*64 h
  float*     part2 = (float*)(part + (size_t)NKC2 * H1 * 64);   // 4*120*64 f
  float*     whb   = part2 + (size_t)4 * H1 * 64;               // 720 f
  float*     out   = (float*)d_out;

  hipLaunchKernelGGL(k_prep, dim3(3), dim3(256), 0, stream, w1, whb);
  hipLaunchKernelGGL(k_conv1, dim3(BB * NT1), dim3(256), 0, stream, x, whb, p1);
  hipLaunchKernelGGL(k_conv2, dim3(BB * 8), dim3(256), 0, stream, p1, w2, p2h);
  hipLaunchKernelGGL(k_fc1, dim3(NKC2), dim3(256), 0, stream, p2h, fc1_w, part);
  hipLaunchKernelGGL(k_fc1red, dim3(4 * H1), dim3(512), 0, stream, part, part2);
  hipLaunchKernelGGL(k_head, dim3(BB), dim3(128), 0, stream, part2, fc1_b, fc2_w, fc2_b,
                     fc3_w, fc3_b, out);
}

// Round 6
// 143.530 us; speedup vs baseline: 1.3757x; 1.0031x over previous
//
#include <hip/hip_runtime.h>

#define BB 64
#define C1 3
#define LIN 8192
#define PAD1 2
#define O1 6
#define KK1 80
#define LP1 4058       // pooled length after conv1(pad=2,K=80) + avgpool2

#define O2 16
#define KK2 3
#define LP2 2028

#define NFLAT 32448    // 16*2028 = 507*64
#define H1 120
#define H2 84
#define NOUT 10

typedef _Float16 h2 __attribute__((ext_vector_type(2)));
typedef _Float16 f16x8 __attribute__((ext_vector_type(8)));
typedef float f32x4 __attribute__((ext_vector_type(4)));
#define BIGH ((_Float16)30000.0f)

__device__ __forceinline__ h2 bch2(float f) { return __builtin_bit_cast(h2, f); }

// ---------------- Kernel 0: pack w1 into half2 pairs (w[2m], w[2m+1]) ----------------
__global__ __launch_bounds__(256) void k_prep(const float* __restrict__ w1,
                                              float* __restrict__ whb) {
  const int idx = threadIdx.x + blockIdx.x * 256;
  if (idx >= (O1 * C1) * (KK1 / 2)) return;
  const int oc = idx / (KK1 / 2);
  const int m  = idx - oc * (KK1 / 2);
  h2 v;
  v.x = (_Float16)w1[oc * KK1 + 2 * m];
  v.y = (_Float16)w1[oc * KK1 + 2 * m + 1];
  whb[idx] = __builtin_bit_cast(float, v);
}

// ---------------- Kernel 1: tropical min-plus conv1 + avgpool2, packed fp16 ----------------
// v2: all operand reads widened to float4 — weights 180 dwordx4 VMEM/thread
// (was 720 dword: issue-bound), x 2 m-steps per LDS float4 (ds_read2_b64).
#define TJ1 256
#define NT1 16
#define DW1 298

__global__ __launch_bounds__(256) void k_conv1(const float* __restrict__ x,
                                               const float* __restrict__ whb,
                                               float* __restrict__ p1) {
  __shared__ float AB[C1][2 * DW1 + 2];
  const int b    = blockIdx.x >> 4;
  const int tile = blockIdx.x & 15;
  const int j0   = tile * TJ1;
  const int T0   = 2 * j0;
  const int tid  = threadIdx.x;

  for (int q = tid; q < C1 * DW1; q += 256) {
    const int c = q / DW1;
    const int d = q - c * DW1;
    const int E = T0 + 2 * d - PAD1;
    const float* xc = x + ((size_t)b * C1 + c) * LIN;
    float f0 = 0.f, f1 = 0.f, f2 = 0.f;
    if ((unsigned)E < LIN) f0 = xc[E];
    if ((unsigned)(E + 1) < LIN) f1 = xc[E + 1];
    if ((unsigned)(E + 2) < LIN) f2 = xc[E + 2];
    h2 A; A.x = (_Float16)f0; A.y = (_Float16)f1;
    h2 Bv; Bv.x = (_Float16)f1; Bv.y = (_Float16)f2;
    AB[c][2 * d]     = __builtin_bit_cast(float, A);
    AB[c][2 * d + 1] = __builtin_bit_cast(float, Bv);
  }
  __syncthreads();

  const int jj = tid;
  const int j  = j0 + jj;

  float s0 = 0.f, s1 = 0.f, s2 = 0.f, s3 = 0.f, s4 = 0.f, s5 = 0.f;

#pragma unroll
  for (int c = 0; c < C1; ++c) {
    h2 aA[O1], aB[O1];
#pragma unroll
    for (int o = 0; o < O1; ++o) {
      aA[o].x = BIGH; aA[o].y = BIGH;
      aB[o].x = BIGH; aB[o].y = BIGH;
    }
#pragma unroll 2
    for (int mc = 0; mc < 10; ++mc) {      // m = mc*4 .. mc*4+3
      float4 xv0 = *(const float4*)&AB[c][2 * (jj + mc * 4)];
      float4 xv1 = *(const float4*)&AB[c][2 * (jj + mc * 4) + 4];
      h2 A0 = bch2(xv0.x), B0 = bch2(xv0.y);
      h2 A1 = bch2(xv0.z), B1 = bch2(xv0.w);
      h2 A2 = bch2(xv1.x), B2 = bch2(xv1.y);
      h2 A3 = bch2(xv1.z), B3 = bch2(xv1.w);
#pragma unroll
      for (int o = 0; o < O1; ++o) {
        float4 wq = *(const float4*)&whb[(o * C1 + c) * (KK1 / 2) + mc * 4];
        h2 w0 = bch2(wq.x), w1v = bch2(wq.y), w2v = bch2(wq.z), w3v = bch2(wq.w);
        aA[o] = __builtin_elementwise_min(aA[o], A0 + w0);
        aB[o] = __builtin_elementwise_min(aB[o], B0 + w0);
        aA[o] = __builtin_elementwise_min(aA[o], A1 + w1v);
        aB[o] = __builtin_elementwise_min(aB[o], B1 + w1v);
        aA[o] = __builtin_elementwise_min(aA[o], A2 + w2v);
        aB[o] = __builtin_elementwise_min(aB[o], B2 + w2v);
        aA[o] = __builtin_elementwise_min(aA[o], A3 + w3v);
        aB[o] = __builtin_elementwise_min(aB[o], B3 + w3v);
      }
    }
    float r[O1];
#pragma unroll
    for (int o = 0; o < O1; ++o)
      r[o] = fminf((float)aA[o].x, (float)aA[o].y) + fminf((float)aB[o].x, (float)aB[o].y);
    s0 += r[0]; s1 += r[1]; s2 += r[2]; s3 += r[3]; s4 += r[4]; s5 += r[5];
  }
  if (j < LP1) {
    float* pb = p1 + (size_t)b * O1 * LP1 + j;
    pb[0 * LP1] = 0.5f * s0;
    pb[1 * LP1] = 0.5f * s1;
    pb[2 * LP1] = 0.5f * s2;
    pb[3 * LP1] = 0.5f * s3;
    pb[4 * LP1] = 0.5f * s4;
    pb[5 * LP1] = 0.5f * s5;
  }
}

// ---------------- Kernel 2: tropical max-plus conv2 (K=3) + avgpool2 -> f16 ----------------
#define T2 256
#define XT2 516

__global__ __launch_bounds__(256) void k_conv2(const float* __restrict__ p1,
                                               const float* __restrict__ w2,
                                               _Float16* __restrict__ p2h) {
  __shared__ float ps[O1][XT2];
  __shared__ float w2s[O2 * O1 * KK2];   // 288 floats
  const int b    = blockIdx.x >> 3;
  const int tile = blockIdx.x & 7;
  const int j0   = tile * T2;
  const int tid  = threadIdx.x;

  for (int idx = tid; idx < O2 * O1 * KK2; idx += 256) w2s[idx] = w2[idx];
  for (int idx = tid; idx < O1 * XT2; idx += 256) {
    int c = idx / XT2;
    int p = idx - c * XT2;
    int t = 2 * j0 + p;
    ps[c][p] = (t < LP1) ? p1[((size_t)b * O1 + c) * LP1 + t] : 0.f;
  }
  __syncthreads();

  const int j = j0 + tid;
  if (j >= LP2) return;
  const int lb = 2 * tid;
  float xv[O1][4];
#pragma unroll
  for (int c = 0; c < O1; ++c) {
    xv[c][0] = ps[c][lb];     xv[c][1] = ps[c][lb + 1];
    xv[c][2] = ps[c][lb + 2]; xv[c][3] = ps[c][lb + 3];
  }
#pragma unroll
  for (int o = 0; o < O2; ++o) {
    float s = 0.f;
#pragma unroll
    for (int c = 0; c < O1; ++c) {
      float w0  = w2s[(o * O1 + c) * KK2 + 0];
      float w1v = w2s[(o * O1 + c) * KK2 + 1];
      float w2v = w2s[(o * O1 + c) * KK2 + 2];
      float m0 = fmaxf(fmaxf(xv[c][0] + w0, xv[c][1] + w1v), xv[c][2] + w2v);
      float m1 = fmaxf(fmaxf(xv[c][1] + w0, xv[c][2] + w1v), xv[c][3] + w2v);
      s += m0 + m1;
    }
    p2h[(size_t)b * NFLAT + o * LP2 + j] = (_Float16)(0.5f * s);
  }
}

// ---------------- Kernel 3: FC1 split-K via MFMA f16 ----------------
#define KC2 64
#define NKC2 507

__global__ __launch_bounds__(256) void k_fc1(const _Float16* __restrict__ p2h,
                                             const float* __restrict__ w,
                                             _Float16* __restrict__ part) {
  __shared__ _Float16 bs[64][KC2];    // [b][k], 8 KB
  const int kc  = blockIdx.x;
  const int k0  = kc * KC2;
  const int tid = threadIdx.x;

#pragma unroll
  for (int r = 0; r < 2; ++r) {
    const int task = tid + 256 * r;        // 0..511
    const int row  = task >> 3;
    const int c4   = task & 7;
    float4 v = *(const float4*)&p2h[(size_t)row * NFLAT + k0 + c4 * 8];
    *(float4*)&bs[row][c4 * 8] = v;
  }
  __syncthreads();

  const int lane = tid & 63;
  const int wid  = tid >> 6;             // 0..3
  const int m_l  = lane & 15;
  const int q    = lane >> 4;            // 0..3
  const int m0   = wid * 32;

  const int rowA0 = m0 + m_l;            // <= 111, always valid
  int rowA1 = m0 + 16 + m_l;             // <= 127; clamp pad rows
  if (rowA1 > H1 - 1) rowA1 = H1 - 1;
  const float* wp0 = w + (size_t)rowA0 * NFLAT + k0 + q * 8;
  const float* wp1 = w + (size_t)rowA1 * NFLAT + k0 + q * 8;

  f32x4 acc[2][4];
#pragma unroll
  for (int t = 0; t < 2; ++t)
#pragma unroll
    for (int nt = 0; nt < 4; ++nt) acc[t][nt] = (f32x4){0.f, 0.f, 0.f, 0.f};

#pragma unroll
  for (int ks = 0; ks < 2; ++ks) {
    float4 a0l = *(const float4*)(wp0 + ks * 32);
    float4 a0h = *(const float4*)(wp0 + ks * 32 + 4);
    float4 a1l = *(const float4*)(wp1 + ks * 32);
    float4 a1h = *(const float4*)(wp1 + ks * 32 + 4);
    f16x8 A0, A1;
    A0[0] = (_Float16)a0l.x; A0[1] = (_Float16)a0l.y;
    A0[2] = (_Float16)a0l.z; A0[3] = (_Float16)a0l.w;
    A0[4] = (_Float16)a0h.x; A0[5] = (_Float16)a0h.y;
    A0[6] = (_Float16)a0h.z; A0[7] = (_Float16)a0h.w;
    A1[0] = (_Float16)a1l.x; A1[1] = (_Float16)a1l.y;
    A1[2] = (_Float16)a1l.z; A1[3] = (_Float16)a1l.w;
    A1[4] = (_Float16)a1h.x; A1[5] = (_Float16)a1h.y;
    A1[6] = (_Float16)a1h.z; A1[7] = (_Float16)a1h.w;
#pragma unroll
    for (int nt = 0; nt < 4; ++nt) {
      f16x8 Bf = *(const f16x8*)&bs[nt * 16 + m_l][ks * 32 + q * 8];
      acc[0][nt] = __builtin_amdgcn_mfma_f32_16x16x32_f16(A0, Bf, acc[0][nt], 0, 0, 0);
      acc[1][nt] = __builtin_amdgcn_mfma_f32_16x16x32_f16(A1, Bf, acc[1][nt], 0, 0, 0);
    }
  }

#pragma unroll
  for (int t = 0; t < 2; ++t)
#pragma unroll
    for (int nt = 0; nt < 4; ++nt)
#pragma unroll
      for (int r = 0; r < 4; ++r) {
        const int i = m0 + t * 16 + q * 4 + r;
        if (i < H1)
          part[((size_t)kc * H1 + i) * 64 + nt * 16 + m_l] = (_Float16)acc[t][nt][r];
      }
}

// ---------------- Kernel 3b: reduce partials -> part2[4][120][64] f32 ----------------
__global__ __launch_bounds__(512) void k_fc1red(const _Float16* __restrict__ part,
                                                float* __restrict__ part2) {
  __shared__ float red[512];
  const int bx  = blockIdx.x;            // 0..479
  const int s   = bx / H1;               // 0..3
  const int i   = bx - s * H1;           // 0..119
  const int tid = threadIdx.x;
  const int b   = tid & 63;
  const int sub = tid >> 6;              // 0..7
  const int kc0 = s * 127;
  const int kc1 = (kc0 + 127 < NKC2) ? kc0 + 127 : NKC2;
  float acc = 0.f;
  for (int kc = kc0 + sub; kc < kc1; kc += 8)
    acc += (float)part[((size_t)kc * H1 + i) * 64 + b];
  red[tid] = acc;
  __syncthreads();
  if (tid < 64) {
    float t = 0.f;
#pragma unroll
    for (int s2 = 0; s2 < 8; ++s2) t += red[b + 64 * s2];
    part2[((size_t)s * H1 + i) * 64 + b] = t;
  }
}

// ---------------- Kernel 4: bias+ReLU, FC2+ReLU, FC3 ----------------
__global__ __launch_bounds__(128) void k_head(const float* __restrict__ part2,
                                              const float* __restrict__ fc1_b,
                                              const float* __restrict__ fc2_w,
                                              const float* __restrict__ fc2_b,
                                              const float* __restrict__ fc3_w,
                                              const float* __restrict__ fc3_b,
                                              float* __restrict__ out) {
  __shared__ float h1s[H1];
  __shared__ float h2s[H2];
  const int b = blockIdx.x;
  const int tid = threadIdx.x;
  if (tid < H1) {
    float v = part2[((size_t)0 * H1 + tid) * 64 + b]
            + part2[((size_t)1 * H1 + tid) * 64 + b]
            + part2[((size_t)2 * H1 + tid) * 64 + b]
            + part2[((size_t)3 * H1 + tid) * 64 + b];
    h1s[tid] = fmaxf(v + fc1_b[tid], 0.f);
  }
  __syncthreads();
  if (tid < H2) {
    float s = fc2_b[tid];
#pragma unroll 4
    for (int n = 0; n < H1; ++n) s += h1s[n] * fc2_w[tid * H1 + n];
    h2s[tid] = fmaxf(s, 0.f);
  }
  __syncthreads();
  if (tid < NOUT) {
    float s = fc3_b[tid];
#pragma unroll 4
    for (int n = 0; n < H2; ++n) s += h2s[n] * fc3_w[tid * H2 + n];
    out[b * NOUT + tid] = s;
  }
}

extern "C" void kernel_launch(void* const* d_in, const int* in_sizes, int n_in,
                              void* d_out, int out_size, void* d_ws, size_t ws_size,
                              hipStream_t stream) {
  const float* x     = (const float*)d_in[0];
  const float* w1    = (const float*)d_in[1];
  const float* w2    = (const float*)d_in[2];
  const float* fc1_w = (const float*)d_in[3];
  const float* fc1_b = (const float*)d_in[4];
  const float* fc2_w = (const float*)d_in[5];
  const float* fc2_b = (const float*)d_in[6];
  const float* fc3_w = (const float*)d_in[7];
  const float* fc3_b = (const float*)d_in[8];

  float* ws = (float*)d_ws;
  float*     p1    = ws;                                        // 1,558,272 f
  _Float16*  p2h   = (_Float16*)(p1 + (size_t)BB * O1 * LP1);   // 2,076,672 h
  _Float16*  part  = p2h + (size_t)BB * NFLAT;                  // 507*120*64 h
  float*     part2 = (float*)(part + (size_t)NKC2 * H1 * 64);   // 4*120*64 f
  float*     whb   = part2 + (size_t)4 * H1 * 64;               // 720 f
  float*     out   = (float*)d_out;

  hipLaunchKernelGGL(k_prep, dim3(3), dim3(256), 0, stream, w1, whb);
  hipLaunchKernelGGL(k_conv1, dim3(BB * NT1), dim3(256), 0, stream, x, whb, p1);
  hipLaunchKernelGGL(k_conv2, dim3(BB * 8), dim3(256), 0, stream, p1, w2, p2h);
  hipLaunchKernelGGL(k_fc1, dim3(NKC2), dim3(256), 0, stream, p2h, fc1_w, part);
  hipLaunchKernelGGL(k_fc1red, dim3(4 * H1), dim3(512), 0, stream, part, part2);
  hipLaunchKernelGGL(k_head, dim3(BB), dim3(128), 0, stream, part2, fc1_b, fc2_w, fc2_b,
                     fc3_w, fc3_b, out);
}